// Round 4
// baseline (3048.677 us; speedup 1.0000x reference)
//
#include <hip/hip_runtime.h>
#include <stdint.h>

typedef _Float16 f16;
typedef _Float16 f16x8 __attribute__((ext_vector_type(8)));
typedef float f32x4 __attribute__((ext_vector_type(4)));

#define TT 256
#define BB 256
#define II 128
#define HH 512
#define G4 2048
#define NGRP 8
#define CNT_STRIDE 16  // u32 per tick slot -> 64B line per (group,tick)
static constexpr size_t BH = (size_t)BB * HH;

// ---------------- helpers ----------------
// agent-coherent u64 access (global_load/store_dwordx2 sc1): served at MALL,
// bypasses non-coherent L1/L2. No cache-wide fences anywhere.
__device__ __forceinline__ uint64_t ld_agent_u64(const uint64_t* p) {
  return __hip_atomic_load(p, __ATOMIC_RELAXED, __HIP_MEMORY_SCOPE_AGENT);
}
__device__ __forceinline__ void st_agent_u64(uint64_t* p, uint64_t v) {
  __hip_atomic_store(p, v, __ATOMIC_RELAXED, __HIP_MEMORY_SCOPE_AGENT);
}
__device__ __forceinline__ uint4 mk4(uint64_t a, uint64_t b) {
  uint4 r;
  r.x = (uint32_t)a; r.y = (uint32_t)(a >> 32);
  r.z = (uint32_t)b; r.w = (uint32_t)(b >> 32);
  return r;
}

__device__ __forceinline__ float fsig(float x) {
  x = fminf(fmaxf(x, -30.f), 30.f);
  float e = __builtin_amdgcn_exp2f(-1.44269504f * x);
  return __builtin_amdgcn_rcpf(1.f + e);
}
__device__ __forceinline__ float ftanh(float x) {
  x = fminf(fmaxf(x, -15.f), 15.f);
  float e = __builtin_amdgcn_exp2f(-2.88539008f * x);  // exp(-2x)
  return (1.f - e) * __builtin_amdgcn_rcpf(1.f + e);
}

// swizzled LDS fragment reads (granule = 16B, XOR with row&7)
__device__ __forceinline__ f16x8 ldfragh(const f16* S, int row, int gi) {
  return *(const f16x8*)(S + row * 512 + ((gi ^ (row & 7)) * 8));
}
__device__ __forceinline__ f16x8 ldfragx(const f16* S, int row, int gi) {
  return *(const f16x8*)(S + row * 128 + ((gi ^ (row & 7)) * 8));
}

__global__ void k_diag(float* out, float val) { out[0] = val; }

// ---------------- x transpose/convert: [B][T][I] f32 -> [T][B][I] f16 ----------------
__global__ __launch_bounds__(256) void k_conv_x(const float* __restrict__ x,
                                                f16* __restrict__ xt) {
  int idx = blockIdx.x * 256 + threadIdx.x;  // unit = 8 floats
  int row = idx >> 4;                        // row = t*B + b
  int ii = (idx & 15) * 8;
  int t = row >> 8, b = row & 255;
  const float4* xs = (const float4*)(x + ((size_t)b * TT + t) * II + ii);
  float4 v0 = xs[0];
  float4 v1 = xs[1];
  f16x8 h;
  h[0] = (f16)v0.x; h[1] = (f16)v0.y; h[2] = (f16)v0.z; h[3] = (f16)v0.w;
  h[4] = (f16)v1.x; h[5] = (f16)v1.y; h[6] = (f16)v1.z; h[7] = (f16)v1.w;
  *(f16x8*)(xt + (size_t)row * II + ii) = h;
}

// ---------------- convert weights to f16, sum biases ----------------
__global__ __launch_bounds__(256) void k_conv_w(
    const float* __restrict__ wih0, const float* __restrict__ whh0,
    const float* __restrict__ wih1, const float* __restrict__ whh1,
    const float* __restrict__ bih0, const float* __restrict__ bhh0,
    const float* __restrict__ bih1, const float* __restrict__ bhh1,
    f16* owih0, f16* owhh0, f16* owih1, f16* owhh1, float* ob0, float* ob1) {
  int i = blockIdx.x * 256 + threadIdx.x;
  if (i < G4 * II) owih0[i] = (f16)wih0[i];
  if (i < G4 * HH) {
    owhh0[i] = (f16)whh0[i];
    owih1[i] = (f16)wih1[i];
    owhh1[i] = (f16)whh1[i];
  }
  if (i < G4) {
    ob0[i] = bih0[i] + bhh0[i];
    ob1[i] = bih1[i] + bhh1[i];
  }
}

// ---------------- fused 2-layer wavefront LSTM ----------------
// 256 blocks = 8 batch-groups (grp=bx>>5, 32 rows) x 32 col-slices (16 h-cols).
// Tick u: layer0 computes step u (if u<T), layer1 computes step u-1 (if u>=1).
// All weights for both layers live in VGPRs (52 f16x8 = 208 regs/lane).
// gates_L0 = x_u@Wih0^T + h1_{u-1}@Whh0^T ; gates_L1 = h1_{u-1}@Wih1^T + h2_{u-2}@Whh1^T.
__global__ __launch_bounds__(256, 1) void k_fused(
    const f16* __restrict__ xt,
    const f16* __restrict__ Wih0, const f16* __restrict__ Whh0,
    const f16* __restrict__ Wih1, const f16* __restrict__ Whh1,
    const float* __restrict__ b0, const float* __restrict__ b1,
    f16* __restrict__ h1r, f16* __restrict__ h2r, uint32_t* __restrict__ cnt) {
  __shared__ __align__(16) f16 h1s[32 * 512];   // 32KB, swizzled
  __shared__ __align__(16) f16 h2s[32 * 512];   // 32KB, swizzled
  __shared__ __align__(16) f16 xs[32 * 128];    // 8KB, swizzled
  __shared__ __align__(16) float gs[2][64][36]; // gate preacts [layer][gcol][row+pad]

  int tid = threadIdx.x;
  int l64 = tid & 63;
  int wid = tid >> 6;        // wave = gate chunk (i,f,g,o)
  int lm = l64 & 15, ls = l64 >> 4;
  int bx = blockIdx.x;
  int grp = bx >> 5;         // 0..7
  int slice = bx & 31;       // 0..31
  int col0 = slice * 16;
  int row0 = grp * 32;
  uint32_t* mycnt = cnt + (size_t)grp * (TT + 1) * CNT_STRIDE;

  // ---- preload weight fragments (plain loads; static data) ----
  int wrow = wid * 512 + col0 + lm;  // gate-col = row of W
  f16x8 wih0f[4], whh0f[16], wih1f[16], whh1f[16];
#pragma unroll
  for (int kk = 0; kk < 4; ++kk)
    wih0f[kk] = *(const f16x8*)(Wih0 + (size_t)wrow * II + kk * 32 + ls * 8);
#pragma unroll
  for (int kk = 0; kk < 16; ++kk) {
    whh0f[kk] = *(const f16x8*)(Whh0 + (size_t)wrow * HH + kk * 32 + ls * 8);
    wih1f[kk] = *(const f16x8*)(Wih1 + (size_t)wrow * HH + kk * 32 + ls * 8);
    whh1f[kk] = *(const f16x8*)(Whh1 + (size_t)wrow * HH + kk * 32 + ls * 8);
  }

  // ---- elementwise role: waves 0-1 -> layer0, waves 2-3 -> layer1 ----
  int el = tid >> 7;         // layer
  int er = (tid >> 2) & 31;  // local batch row
  int eq = tid & 3;          // col quad (4 consecutive cols)
  const float* bsrc = el ? b1 : b0;
  float bias[4][4];
#pragma unroll
  for (int g = 0; g < 4; ++g)
#pragma unroll
    for (int j = 0; j < 4; ++j) bias[g][j] = bsrc[g * HH + col0 + eq * 4 + j];
  float cst[4] = {0.f, 0.f, 0.f, 0.f};
  f16* ering = el ? h2r : h1r;

  // staging role: row = tid>>3 (0..31), 8 granules of 16B per h-tile row-part
  int sr = tid >> 3;
  int sg0 = (tid & 7) * 8;

#pragma unroll 1
  for (int u = 0; u <= TT; ++u) {
    // stage x_u first (independent of handshake; plain loads, L2-served)
    if (u < TT) {
      const uint4* src = (const uint4*)(xt + ((size_t)u * BB + row0 + sr) * II);
      uint4* dst = (uint4*)xs;
      int gx = (tid & 7) * 2;
#pragma unroll
      for (int q = 0; q < 2; ++q) {
        int gi = gx + q;
        dst[sr * 16 + (gi ^ (sr & 7))] = src[gi];
      }
    }
    if (u > 0) {
      // poll: all 32 peer blocks of this group stored tick u-1 (broadcast load)
      int guard = 0;
      while (__hip_atomic_load(&mycnt[(u - 1) * CNT_STRIDE], __ATOMIC_RELAXED,
                               __HIP_MEMORY_SCOPE_AGENT) < 32u) {
        if (++guard > 4000000) break;  // safety net
      }
      asm volatile("" ::: "memory");
      {  // stage h1_{u-1} (slot (u-1)&1) -> swizzled LDS
        const uint64_t* src = (const uint64_t*)(h1r + (size_t)((u - 1) & 1) * BH +
                                                (size_t)(row0 + sr) * HH);
        uint4* dst = (uint4*)h1s;
#pragma unroll
        for (int q = 0; q < 8; ++q) {
          int gi = sg0 + q;
          uint64_t a = ld_agent_u64(src + gi * 2);
          uint64_t b = ld_agent_u64(src + gi * 2 + 1);
          dst[sr * 64 + (gi ^ (sr & 7))] = mk4(a, b);
        }
      }
      if (u >= 2) {  // stage h2_{u-2} (slot (u-2)&1 == u&1)
        const uint64_t* src = (const uint64_t*)(h2r + (size_t)(u & 1) * BH +
                                                (size_t)(row0 + sr) * HH);
        uint4* dst = (uint4*)h2s;
#pragma unroll
        for (int q = 0; q < 8; ++q) {
          int gi = sg0 + q;
          uint64_t a = ld_agent_u64(src + gi * 2);
          uint64_t b = ld_agent_u64(src + gi * 2 + 1);
          dst[sr * 64 + (gi ^ (sr & 7))] = mk4(a, b);
        }
      }
    }
    __syncthreads();

    // ---- MFMA: acc[layer][mfrag], N=16 gate-cols per wave ----
    f32x4 a0f0 = {0.f, 0.f, 0.f, 0.f}, a0f1 = {0.f, 0.f, 0.f, 0.f};
    f32x4 a1f0 = {0.f, 0.f, 0.f, 0.f}, a1f1 = {0.f, 0.f, 0.f, 0.f};
    if (u < TT) {  // L0 x-projection, K=128
#pragma unroll
      for (int kk = 0; kk < 4; ++kk) {
        f16x8 xA = ldfragx(xs, lm, kk * 4 + ls);
        f16x8 xB = ldfragx(xs, 16 + lm, kk * 4 + ls);
        a0f0 = __builtin_amdgcn_mfma_f32_16x16x32_f16(xA, wih0f[kk], a0f0, 0, 0, 0);
        a0f1 = __builtin_amdgcn_mfma_f32_16x16x32_f16(xB, wih0f[kk], a0f1, 0, 0, 0);
      }
    }
    if (u > 0) {  // h1_{u-1} feeds L0 recurrence AND L1 input projection
#pragma unroll
      for (int kk = 0; kk < 16; ++kk) {
        f16x8 hA = ldfragh(h1s, lm, kk * 4 + ls);
        f16x8 hB = ldfragh(h1s, 16 + lm, kk * 4 + ls);
        if (u < TT) {
          a0f0 = __builtin_amdgcn_mfma_f32_16x16x32_f16(hA, whh0f[kk], a0f0, 0, 0, 0);
          a0f1 = __builtin_amdgcn_mfma_f32_16x16x32_f16(hB, whh0f[kk], a0f1, 0, 0, 0);
        }
        a1f0 = __builtin_amdgcn_mfma_f32_16x16x32_f16(hA, wih1f[kk], a1f0, 0, 0, 0);
        a1f1 = __builtin_amdgcn_mfma_f32_16x16x32_f16(hB, wih1f[kk], a1f1, 0, 0, 0);
      }
      if (u >= 2) {  // L1 recurrence over h2_{u-2}
#pragma unroll
        for (int kk = 0; kk < 16; ++kk) {
          f16x8 hA = ldfragh(h2s, lm, kk * 4 + ls);
          f16x8 hB = ldfragh(h2s, 16 + lm, kk * 4 + ls);
          a1f0 = __builtin_amdgcn_mfma_f32_16x16x32_f16(hA, whh1f[kk], a1f0, 0, 0, 0);
          a1f1 = __builtin_amdgcn_mfma_f32_16x16x32_f16(hB, whh1f[kk], a1f1, 0, 0, 0);
        }
      }
    }
    // acc -> gs[layer][gcol][row]; C layout: col=lane&15, row=(lane>>4)*4+reg
    *(f32x4*)&gs[0][wid * 16 + lm][ls * 4] = a0f0;
    *(f32x4*)&gs[0][wid * 16 + lm][16 + ls * 4] = a0f1;
    *(f32x4*)&gs[1][wid * 16 + lm][ls * 4] = a1f0;
    *(f32x4*)&gs[1][wid * 16 + lm][16 + ls * 4] = a1f1;
    __syncthreads();

    // ---- elementwise LSTM cell: 4 cells per thread (layer el, row er, cols eq*4..+3)
    bool act = el ? (u >= 1) : (u < TT);
    if (act) {
      int t_l = el ? (u - 1) : u;
      int slot = t_l & 1;
      union { uint64_t v; unsigned short us[4]; } pk;
#pragma unroll
      for (int j = 0; j < 4; ++j) {
        int cl = eq * 4 + j;
        float pi = gs[el][0 * 16 + cl][er] + bias[0][j];
        float pf = gs[el][1 * 16 + cl][er] + bias[1][j];
        float pg = gs[el][2 * 16 + cl][er] + bias[2][j];
        float po = gs[el][3 * 16 + cl][er] + bias[3][j];
        float ig = fsig(pi), fg = fsig(pf), gg = ftanh(pg), og = fsig(po);
        cst[j] = fg * cst[j] + ig * gg;
        pk.us[j] = __builtin_bit_cast(unsigned short, (f16)(og * ftanh(cst[j])));
      }
      uint64_t* dst = (uint64_t*)(ering + (size_t)slot * BH +
                                  (size_t)(row0 + er) * HH + col0 + eq * 4);
      st_agent_u64(dst, pk.v);
    }
    asm volatile("s_waitcnt vmcnt(0)" ::: "memory");  // h stores reached MALL
    __syncthreads();
    if (u < TT && tid == 0)
      __hip_atomic_fetch_add(&mycnt[u * CNT_STRIDE], 1u, __ATOMIC_RELAXED,
                             __HIP_MEMORY_SCOPE_AGENT);
  }
}

// ---------------- FC head: out[b] = h2_last[b][:] . fcw + fcb ----------------
__global__ __launch_bounds__(64) void k_fc(const f16* __restrict__ h2,
                                           const float* __restrict__ fcw,
                                           const float* __restrict__ fcb,
                                           float* __restrict__ out) {
  int b = blockIdx.x;
  int l = threadIdx.x;
  f16x8 hv = *(const f16x8*)(h2 + (size_t)b * HH + l * 8);
  float4 w0 = ((const float4*)fcw)[l * 2];
  float4 w1 = ((const float4*)fcw)[l * 2 + 1];
  float s = (float)hv[0] * w0.x + (float)hv[1] * w0.y + (float)hv[2] * w0.z +
            (float)hv[3] * w0.w + (float)hv[4] * w1.x + (float)hv[5] * w1.y +
            (float)hv[6] * w1.z + (float)hv[7] * w1.w;
#pragma unroll
  for (int off = 32; off > 0; off >>= 1) s += __shfl_down(s, off);
  if (l == 0) out[b] = s + fcb[0];
}

// ---------------- launch ----------------
extern "C" void kernel_launch(void* const* d_in, const int* in_sizes, int n_in,
                              void* d_out, int out_size, void* d_ws, size_t ws_size,
                              hipStream_t stream) {
  (void)in_sizes; (void)n_in; (void)out_size;

  const float* x    = (const float*)d_in[0];
  const float* wih0 = (const float*)d_in[1];
  const float* whh0 = (const float*)d_in[2];
  const float* bih0 = (const float*)d_in[3];
  const float* bhh0 = (const float*)d_in[4];
  const float* wih1 = (const float*)d_in[5];
  const float* whh1 = (const float*)d_in[6];
  const float* bih1 = (const float*)d_in[7];
  const float* bhh1 = (const float*)d_in[8];
  const float* fcw  = (const float*)d_in[9];
  const float* fcb  = (const float*)d_in[10];

  const size_t SZ_XT   = (size_t)TT * BB * II * 2;              // 16.8 MB
  const size_t SZ_WIH0 = (size_t)G4 * II * 2;
  const size_t SZ_W    = (size_t)G4 * HH * 2;
  const size_t SZ_B    = (size_t)G4 * 4;
  const size_t SZ_RING = (size_t)2 * BH * 2;
  const size_t SZ_CNT  = (size_t)NGRP * (TT + 1) * CNT_STRIDE * 4;
  const size_t TOTAL = SZ_XT + SZ_WIH0 + 3 * SZ_W + 2 * SZ_B + 2 * SZ_RING + SZ_CNT;

  if (ws_size < TOTAL) {
    k_diag<<<1, 1, 0, stream>>>((float*)d_out, (float)(ws_size >> 20));
    return;
  }

  char* ws = (char*)d_ws;
  size_t off = 0;
  f16* xt    = (f16*)(ws + off); off += SZ_XT;
  f16* cwih0 = (f16*)(ws + off); off += SZ_WIH0;
  f16* cwhh0 = (f16*)(ws + off); off += SZ_W;
  f16* cwih1 = (f16*)(ws + off); off += SZ_W;
  f16* cwhh1 = (f16*)(ws + off); off += SZ_W;
  float* b0  = (float*)(ws + off); off += SZ_B;
  float* b1  = (float*)(ws + off); off += SZ_B;
  f16* h1r   = (f16*)(ws + off); off += SZ_RING;
  f16* h2r   = (f16*)(ws + off); off += SZ_RING;
  uint32_t* cnt = (uint32_t*)(ws + off); off += SZ_CNT;

  hipMemsetAsync(cnt, 0, SZ_CNT, stream);
  k_conv_w<<<4096, 256, 0, stream>>>(wih0, whh0, wih1, whh1, bih0, bhh0, bih1, bhh1,
                                     cwih0, cwhh0, cwih1, cwhh1, b0, b1);
  k_conv_x<<<4096, 256, 0, stream>>>(x, xt);
  k_fused<<<256, 256, 0, stream>>>(xt, cwih0, cwhh0, cwih1, cwhh1, b0, b1,
                                   h1r, h2r, cnt);
  // h2_255 is in ring slot (255&1)==1
  k_fc<<<256, 64, 0, stream>>>(h2r + BH, fcw, fcb, (float*)d_out);
}

// Round 5
// 1559.211 us; speedup vs baseline: 1.9553x; 1.9553x over previous
//
#include <hip/hip_runtime.h>
#include <stdint.h>

typedef _Float16 f16;
typedef _Float16 f16x8 __attribute__((ext_vector_type(8)));
typedef float f32x4 __attribute__((ext_vector_type(4)));

#define TT 256
#define BB 256
#define II 128
#define HH 512
#define G4 2048
#define NGRP 8
static constexpr size_t BH = (size_t)BB * HH;

// ---------------- helpers ----------------
// agent-coherent access (global_load/store sc1): served at the device
// coherence point (MALL), bypasses non-coherent L1/L2. No cache-wide fences.
__device__ __forceinline__ uint64_t ld_agent_u64(const uint64_t* p) {
  return __hip_atomic_load(p, __ATOMIC_RELAXED, __HIP_MEMORY_SCOPE_AGENT);
}
__device__ __forceinline__ void st_agent_u64(uint64_t* p, uint64_t v) {
  __hip_atomic_store(p, v, __ATOMIC_RELAXED, __HIP_MEMORY_SCOPE_AGENT);
}
__device__ __forceinline__ void st_agent_u16(uint16_t* p, uint16_t v) {
  __hip_atomic_store(p, v, __ATOMIC_RELAXED, __HIP_MEMORY_SCOPE_AGENT);
}
__device__ __forceinline__ uint4 mk4(uint64_t a, uint64_t b) {
  uint4 r;
  r.x = (uint32_t)a; r.y = (uint32_t)(a >> 32);
  r.z = (uint32_t)b; r.w = (uint32_t)(b >> 32);
  return r;
}

__device__ __forceinline__ float fsig(float x) {
  x = fminf(fmaxf(x, -30.f), 30.f);
  float e = __builtin_amdgcn_exp2f(-1.44269504f * x);
  return __builtin_amdgcn_rcpf(1.f + e);
}
__device__ __forceinline__ float ftanh(float x) {
  x = fminf(fmaxf(x, -15.f), 15.f);
  float e = __builtin_amdgcn_exp2f(-2.88539008f * x);  // exp(-2x)
  return (1.f - e) * __builtin_amdgcn_rcpf(1.f + e);
}

// swizzled LDS fragment reads (granule = 16B, XOR with row&7)
__device__ __forceinline__ f16x8 ldfragh(const f16* S, int row, int gi) {
  return *(const f16x8*)(S + row * 512 + ((gi ^ (row & 7)) * 8));
}
__device__ __forceinline__ f16x8 ldfragx(const f16* S, int row, int gi) {
  return *(const f16x8*)(S + row * 128 + ((gi ^ (row & 7)) * 8));
}

__global__ void k_diag(float* out, float val) { out[0] = val; }

// ---------------- x transpose/convert: [B][T][I] f32 -> [T][B][I] f16 ----------------
__global__ __launch_bounds__(256) void k_conv_x(const float* __restrict__ x,
                                                f16* __restrict__ xt) {
  int idx = blockIdx.x * 256 + threadIdx.x;  // unit = 8 floats
  int row = idx >> 4;                        // row = t*B + b
  int ii = (idx & 15) * 8;
  int t = row >> 8, b = row & 255;
  const float4* xs = (const float4*)(x + ((size_t)b * TT + t) * II + ii);
  float4 v0 = xs[0];
  float4 v1 = xs[1];
  f16x8 h;
  h[0] = (f16)v0.x; h[1] = (f16)v0.y; h[2] = (f16)v0.z; h[3] = (f16)v0.w;
  h[4] = (f16)v1.x; h[5] = (f16)v1.y; h[6] = (f16)v1.z; h[7] = (f16)v1.w;
  *(f16x8*)(xt + (size_t)row * II + ii) = h;
}

// ---------------- convert weights to f16, sum biases ----------------
__global__ __launch_bounds__(256) void k_conv_w(
    const float* __restrict__ wih0, const float* __restrict__ whh0,
    const float* __restrict__ wih1, const float* __restrict__ whh1,
    const float* __restrict__ bih0, const float* __restrict__ bhh0,
    const float* __restrict__ bih1, const float* __restrict__ bhh1,
    f16* owih0, f16* owhh0, f16* owih1, f16* owhh1, float* ob0, float* ob1) {
  int i = blockIdx.x * 256 + threadIdx.x;
  if (i < G4 * II) owih0[i] = (f16)wih0[i];
  if (i < G4 * HH) {
    owhh0[i] = (f16)whh0[i];
    owih1[i] = (f16)wih1[i];
    owhh1[i] = (f16)whh1[i];
  }
  if (i < G4) {
    ob0[i] = bih0[i] + bhh0[i];
    ob1[i] = bih1[i] + bhh1[i];
  }
}

// ---------------- fused 2-layer wavefront LSTM ----------------
// 256 blocks = 8 batch-groups (grp=bx&7 -> one XCD per group, perf-only) x 32
// col-slices (slice=bx>>3, 16 h-cols). Tick u: L0 computes step u (u<T), L1
// computes step u-1 (u>=1). All weights in VGPRs (52 f16x8 = 208 regs/lane).
// Handshake: per-(group,tick) 64B flag line, one u16 slot per slice. Parallel
// sc1 stores (no RMW); pollers load 4 u64 words with s_sleep backoff.
__global__ __launch_bounds__(256, 1) void k_fused(
    const f16* __restrict__ xt,
    const f16* __restrict__ Wih0, const f16* __restrict__ Whh0,
    const f16* __restrict__ Wih1, const f16* __restrict__ Whh1,
    const float* __restrict__ b0, const float* __restrict__ b1,
    f16* __restrict__ h1r, f16* __restrict__ h2r, uint16_t* __restrict__ flags) {
  __shared__ __align__(16) f16 h1s[32 * 512];   // 32KB, swizzled
  __shared__ __align__(16) f16 h2s[32 * 512];   // 32KB, swizzled
  __shared__ __align__(16) f16 xs[32 * 128];    // 8KB, swizzled
  __shared__ __align__(16) float gs[2][64][36]; // gate preacts [layer][gcol][row+pad]

  int tid = threadIdx.x;
  int l64 = tid & 63;
  int wid = tid >> 6;        // wave = gate chunk (i,f,g,o)
  int lm = l64 & 15, ls = l64 >> 4;
  int bx = blockIdx.x;
  int grp = bx & 7;          // 0..7 (likely one XCD per group)
  int slice = bx >> 3;       // 0..31
  int col0 = slice * 16;
  int row0 = grp * 32;

  // ---- preload weight fragments (plain loads; static data) ----
  int wrow = wid * 512 + col0 + lm;  // gate-col = row of W
  f16x8 wih0f[4], whh0f[16], wih1f[16], whh1f[16];
#pragma unroll
  for (int kk = 0; kk < 4; ++kk)
    wih0f[kk] = *(const f16x8*)(Wih0 + (size_t)wrow * II + kk * 32 + ls * 8);
#pragma unroll
  for (int kk = 0; kk < 16; ++kk) {
    whh0f[kk] = *(const f16x8*)(Whh0 + (size_t)wrow * HH + kk * 32 + ls * 8);
    wih1f[kk] = *(const f16x8*)(Wih1 + (size_t)wrow * HH + kk * 32 + ls * 8);
    whh1f[kk] = *(const f16x8*)(Whh1 + (size_t)wrow * HH + kk * 32 + ls * 8);
  }

  // ---- elementwise role: threads<128 -> layer0, >=128 -> layer1 ----
  int el = tid >> 7;         // layer
  int er = (tid >> 2) & 31;  // local batch row
  int eq = tid & 3;          // col quad (4 consecutive cols)
  const float* bsrc = el ? b1 : b0;
  float bias[4][4];
#pragma unroll
  for (int g = 0; g < 4; ++g)
#pragma unroll
    for (int j = 0; j < 4; ++j) bias[g][j] = bsrc[g * HH + col0 + eq * 4 + j];
  float cst[4] = {0.f, 0.f, 0.f, 0.f};
  f16* ering = el ? h2r : h1r;

  // staging role: row = tid>>3 (0..31), granule g = (tid&7) + q*8 (16B units)
  int sr = tid >> 3;
  int gx = tid & 7;
  const uint64_t kTarget = 0x0001000100010001ULL;

#pragma unroll 1
  for (int u = 0; u <= TT; ++u) {
    // prefetch x_u into regs (plain loads; hides under poll)
    uint4 xv0, xv1;
    if (u < TT) {
      const uint4* src = (const uint4*)(xt + ((size_t)u * BB + row0 + sr) * II);
      xv0 = src[gx];
      xv1 = src[gx + 8];
    }
    if (u > 0) {
      // poll the (grp, u-1) flag line: 32 u16 slots == 1
      const uint64_t* fl =
          (const uint64_t*)(flags + ((size_t)grp * (TT + 1) + (u - 1)) * 32);
      int guard = 0;
      for (;;) {
        uint64_t v = ld_agent_u64(fl + (l64 & 3));
        if (__all(v == kTarget)) break;
        if (++guard > 200000) break;  // deadlock safety net
        __builtin_amdgcn_s_sleep(1);  // backoff: cut MALL poll traffic
      }
      asm volatile("" ::: "memory");  // no hoisting data loads above poll
      // ---- issue ALL h loads first (MLP), then LDS writes ----
      const uint64_t* s1 = (const uint64_t*)(h1r + (size_t)((u - 1) & 1) * BH +
                                             (size_t)(row0 + sr) * HH);
      uint64_t va[16], vb[16];
#pragma unroll
      for (int q = 0; q < 8; ++q) {
        int gi = gx + q * 8;
        va[2 * q]     = ld_agent_u64(s1 + gi * 2);
        va[2 * q + 1] = ld_agent_u64(s1 + gi * 2 + 1);
      }
      if (u >= 2) {
        const uint64_t* s2 = (const uint64_t*)(h2r + (size_t)(u & 1) * BH +
                                               (size_t)(row0 + sr) * HH);
#pragma unroll
        for (int q = 0; q < 8; ++q) {
          int gi = gx + q * 8;
          vb[2 * q]     = ld_agent_u64(s2 + gi * 2);
          vb[2 * q + 1] = ld_agent_u64(s2 + gi * 2 + 1);
        }
      }
      uint4* d1 = (uint4*)h1s;
#pragma unroll
      for (int q = 0; q < 8; ++q) {
        int gi = gx + q * 8;
        d1[sr * 64 + (gi ^ (sr & 7))] = mk4(va[2 * q], va[2 * q + 1]);
      }
      if (u >= 2) {
        uint4* d2 = (uint4*)h2s;
#pragma unroll
        for (int q = 0; q < 8; ++q) {
          int gi = gx + q * 8;
          d2[sr * 64 + (gi ^ (sr & 7))] = mk4(vb[2 * q], vb[2 * q + 1]);
        }
      }
    }
    if (u < TT) {  // x -> swizzled LDS
      uint4* dx = (uint4*)xs;
      dx[sr * 16 + (gx ^ (sr & 7))] = xv0;
      dx[sr * 16 + ((gx + 8) ^ (sr & 7))] = xv1;
    }
    __syncthreads();

    // ---- MFMA: wave wid computes gate chunk wid, 16 cols, 32 rows ----
    f32x4 a0f0 = {0.f, 0.f, 0.f, 0.f}, a0f1 = {0.f, 0.f, 0.f, 0.f};
    f32x4 a1f0 = {0.f, 0.f, 0.f, 0.f}, a1f1 = {0.f, 0.f, 0.f, 0.f};
    if (u < TT) {  // L0 x-projection, K=128
#pragma unroll
      for (int kk = 0; kk < 4; ++kk) {
        f16x8 xA = ldfragx(xs, lm, kk * 4 + ls);
        f16x8 xB = ldfragx(xs, 16 + lm, kk * 4 + ls);
        a0f0 = __builtin_amdgcn_mfma_f32_16x16x32_f16(xA, wih0f[kk], a0f0, 0, 0, 0);
        a0f1 = __builtin_amdgcn_mfma_f32_16x16x32_f16(xB, wih0f[kk], a0f1, 0, 0, 0);
      }
    }
    if (u > 0) {  // h1_{u-1} feeds L0 recurrence AND L1 input projection
#pragma unroll
      for (int kk = 0; kk < 16; ++kk) {
        f16x8 hA = ldfragh(h1s, lm, kk * 4 + ls);
        f16x8 hB = ldfragh(h1s, 16 + lm, kk * 4 + ls);
        if (u < TT) {
          a0f0 = __builtin_amdgcn_mfma_f32_16x16x32_f16(hA, whh0f[kk], a0f0, 0, 0, 0);
          a0f1 = __builtin_amdgcn_mfma_f32_16x16x32_f16(hB, whh0f[kk], a0f1, 0, 0, 0);
        }
        a1f0 = __builtin_amdgcn_mfma_f32_16x16x32_f16(hA, wih1f[kk], a1f0, 0, 0, 0);
        a1f1 = __builtin_amdgcn_mfma_f32_16x16x32_f16(hB, wih1f[kk], a1f1, 0, 0, 0);
      }
      if (u >= 2) {  // L1 recurrence over h2_{u-2}
#pragma unroll
        for (int kk = 0; kk < 16; ++kk) {
          f16x8 hA = ldfragh(h2s, lm, kk * 4 + ls);
          f16x8 hB = ldfragh(h2s, 16 + lm, kk * 4 + ls);
          a1f0 = __builtin_amdgcn_mfma_f32_16x16x32_f16(hA, whh1f[kk], a1f0, 0, 0, 0);
          a1f1 = __builtin_amdgcn_mfma_f32_16x16x32_f16(hB, whh1f[kk], a1f1, 0, 0, 0);
        }
      }
    }
    // acc -> gs[layer][gcol][row]; C layout: col=lane&15, row=(lane>>4)*4+reg
    *(f32x4*)&gs[0][wid * 16 + lm][ls * 4] = a0f0;
    *(f32x4*)&gs[0][wid * 16 + lm][16 + ls * 4] = a0f1;
    *(f32x4*)&gs[1][wid * 16 + lm][ls * 4] = a1f0;
    *(f32x4*)&gs[1][wid * 16 + lm][16 + ls * 4] = a1f1;
    __syncthreads();

    // ---- elementwise LSTM cell: 4 cells/thread (layer el, row er, cols eq*4..+3)
    bool act = el ? (u >= 1) : (u < TT);
    if (act) {
      int t_l = el ? (u - 1) : u;
      int slot = t_l & 1;
      union { uint64_t v; unsigned short us[4]; } pk;
#pragma unroll
      for (int j = 0; j < 4; ++j) {
        int cl = eq * 4 + j;
        float pi = gs[el][0 * 16 + cl][er] + bias[0][j];
        float pf = gs[el][1 * 16 + cl][er] + bias[1][j];
        float pg = gs[el][2 * 16 + cl][er] + bias[2][j];
        float po = gs[el][3 * 16 + cl][er] + bias[3][j];
        float ig = fsig(pi), fg = fsig(pf), gg = ftanh(pg), og = fsig(po);
        cst[j] = fg * cst[j] + ig * gg;
        pk.us[j] = __builtin_bit_cast(unsigned short, (f16)(og * ftanh(cst[j])));
      }
      uint64_t* dst = (uint64_t*)(ering + (size_t)slot * BH +
                                  (size_t)(row0 + er) * HH + col0 + eq * 4);
      st_agent_u64(dst, pk.v);
    }
    asm volatile("s_waitcnt vmcnt(0)" ::: "memory");  // h stores reached MALL
    __syncthreads();                                  // all waves drained
    if (u < TT && tid == 0)  // parallel flag store: no RMW
      st_agent_u16(flags + ((size_t)grp * (TT + 1) + u) * 32 + slice, 1u);
  }
}

// ---------------- FC head: out[b] = h2_last[b][:] . fcw + fcb ----------------
__global__ __launch_bounds__(64) void k_fc(const f16* __restrict__ h2,
                                           const float* __restrict__ fcw,
                                           const float* __restrict__ fcb,
                                           float* __restrict__ out) {
  int b = blockIdx.x;
  int l = threadIdx.x;
  f16x8 hv = *(const f16x8*)(h2 + (size_t)b * HH + l * 8);
  float4 w0 = ((const float4*)fcw)[l * 2];
  float4 w1 = ((const float4*)fcw)[l * 2 + 1];
  float s = (float)hv[0] * w0.x + (float)hv[1] * w0.y + (float)hv[2] * w0.z +
            (float)hv[3] * w0.w + (float)hv[4] * w1.x + (float)hv[5] * w1.y +
            (float)hv[6] * w1.z + (float)hv[7] * w1.w;
#pragma unroll
  for (int off = 32; off > 0; off >>= 1) s += __shfl_down(s, off);
  if (l == 0) out[b] = s + fcb[0];
}

// ---------------- launch ----------------
extern "C" void kernel_launch(void* const* d_in, const int* in_sizes, int n_in,
                              void* d_out, int out_size, void* d_ws, size_t ws_size,
                              hipStream_t stream) {
  (void)in_sizes; (void)n_in; (void)out_size;

  const float* x    = (const float*)d_in[0];
  const float* wih0 = (const float*)d_in[1];
  const float* whh0 = (const float*)d_in[2];
  const float* bih0 = (const float*)d_in[3];
  const float* bhh0 = (const float*)d_in[4];
  const float* wih1 = (const float*)d_in[5];
  const float* whh1 = (const float*)d_in[6];
  const float* bih1 = (const float*)d_in[7];
  const float* bhh1 = (const float*)d_in[8];
  const float* fcw  = (const float*)d_in[9];
  const float* fcb  = (const float*)d_in[10];

  const size_t SZ_XT   = (size_t)TT * BB * II * 2;              // 16.8 MB
  const size_t SZ_WIH0 = (size_t)G4 * II * 2;
  const size_t SZ_W    = (size_t)G4 * HH * 2;
  const size_t SZ_B    = (size_t)G4 * 4;
  const size_t SZ_RING = (size_t)2 * BH * 2;
  const size_t SZ_FLG  = (size_t)NGRP * (TT + 1) * 64;          // 64B line per (grp,tick)
  const size_t TOTAL = SZ_XT + SZ_WIH0 + 3 * SZ_W + 2 * SZ_B + 2 * SZ_RING + SZ_FLG;

  if (ws_size < TOTAL) {
    k_diag<<<1, 1, 0, stream>>>((float*)d_out, (float)(ws_size >> 20));
    return;
  }

  char* ws = (char*)d_ws;
  size_t off = 0;
  f16* xt    = (f16*)(ws + off); off += SZ_XT;
  f16* cwih0 = (f16*)(ws + off); off += SZ_WIH0;
  f16* cwhh0 = (f16*)(ws + off); off += SZ_W;
  f16* cwih1 = (f16*)(ws + off); off += SZ_W;
  f16* cwhh1 = (f16*)(ws + off); off += SZ_W;
  float* b0  = (float*)(ws + off); off += SZ_B;
  float* b1  = (float*)(ws + off); off += SZ_B;
  f16* h1r   = (f16*)(ws + off); off += SZ_RING;
  f16* h2r   = (f16*)(ws + off); off += SZ_RING;
  uint16_t* flags = (uint16_t*)(ws + off); off += SZ_FLG;

  hipMemsetAsync(flags, 0, SZ_FLG, stream);
  k_conv_w<<<4096, 256, 0, stream>>>(wih0, whh0, wih1, whh1, bih0, bhh0, bih1, bhh1,
                                     cwih0, cwhh0, cwih1, cwhh1, b0, b1);
  k_conv_x<<<4096, 256, 0, stream>>>(x, xt);
  k_fused<<<256, 256, 0, stream>>>(xt, cwih0, cwhh0, cwih1, cwhh1, b0, b1,
                                   h1r, h2r, flags);
  // h2_255 is in ring slot (255&1)==1
  k_fc<<<256, 64, 0, stream>>>(h2r + BH, fcw, fcb, (float*)d_out);
}